// Round 5
// baseline (266.121 us; speedup 1.0000x reference)
//
#include <hip/hip_runtime.h>
#include <math.h>

#define NT 1024            // one block, 16 waves, one CU
#define NB 4096            // value buckets; monotone bucketing => exact algorithm
#define EPT 16             // elements per thread (NT*EPT == n)

// Entire SurvPLE loss in ONE kernel, ONE workgroup.
// risk[i] = sum_j exp(theta_j)*[T_j >= T_i]
//         = suffixE[bucket(T_i)+1] + exact scan over same-bucket members.
__global__ void __launch_bounds__(NT)
surv_one(const float* __restrict__ theta,
         const float* __restrict__ T,
         const float* __restrict__ events,
         float* __restrict__ out,
         float* __restrict__ sortedT,   // ws [n]
         float* __restrict__ sortedE,   // ws [n]
         int n) {
    __shared__ int   cnt[NB + 1];   // counts -> (in place) exclusive prefix offsets
    __shared__ float be[NB + 1];    // bucketE -> (in place) inclusive suffix sums
    __shared__ int   ci[NT];        // scan temp (chunk prefix)
    __shared__ float ce[NT];        // scan temp (chunk suffix)
    __shared__ float red[NT];       // final reduction

    const int t = threadIdx.x;
    const float scale = (float)NB / 12.0f;

    // ---- P0: zero LDS histogram ----
    for (int b = t; b <= NB; b += NT) { cnt[b] = 0; be[b] = 0.f; }
    __syncthreads();

    // ---- P1: exp + bucket + LDS histogram (rank via LDS atomic) ----
    float Tv[EPT], Ev[EPT];
    int   Bv[EPT], Rv[EPT];
#pragma unroll
    for (int k = 0; k < EPT; ++k) {
        const int i = k * NT + t;            // coalesced
        const float Tg = T[i];
        const float E  = expf(theta[i]);
        int b = (int)((Tg + 6.0f) * scale);  // monotone in Tg -> order-exact
        b = min(max(b, 0), NB - 1);
        Tv[k] = Tg; Ev[k] = E; Bv[k] = b;
        Rv[k] = atomicAdd(&cnt[b], 1);
        atomicAdd(&be[b], E);
    }
    __syncthreads();

    // ---- P2: in-LDS scans: exclusive prefix(cnt), inclusive suffix(be) ----
    const int CH = NB / NT;                  // 4 buckets per thread
    const int base = t * CH;
    int cs = 0; float es = 0.f;
#pragma unroll
    for (int k = 0; k < CH; ++k) { cs += cnt[base + k]; es += be[base + k]; }
    ci[t] = cs; ce[t] = es;
    __syncthreads();
    for (int s = 1; s < NT; s <<= 1) {       // Hillis-Steele, 10 steps
        const int   a = (t >= s)      ? ci[t - s] : 0;
        const float f = (t + s < NT)  ? ce[t + s] : 0.f;
        __syncthreads();
        ci[t] += a; ce[t] += f;
        __syncthreads();
    }
    {
        int run = ci[t] - cs;                // exclusive prefix of chunk sums
        float rs = ce[t] - es;               // suffix strictly after this chunk
#pragma unroll
        for (int k = 0; k < CH; ++k) { const int c = cnt[base + k]; cnt[base + k] = run; run += c; }
#pragma unroll
        for (int k = CH - 1; k >= 0; --k) { rs += be[base + k]; be[base + k] = rs; }
    }
    if (t == 0) { cnt[NB] = n; be[NB] = 0.f; }
    __syncthreads();

    // ---- P3: counting-sort scatter to workspace ----
#pragma unroll
    for (int k = 0; k < EPT; ++k) {
        const int pos = cnt[Bv[k]] + Rv[k];
        sortedT[pos] = Tv[k];
        sortedE[pos] = Ev[k];
    }
    __threadfence();                         // make global scatter visible in-block
    __syncthreads();

    // ---- P4: risk + term, accumulate locally ----
    float local = 0.f;
#pragma unroll
    for (int k = 0; k < EPT; ++k) {
        const int i = k * NT + t;
        const int b = Bv[k];
        const float Ti = Tv[k];
        float risk = be[b + 1];              // sum over all strictly-higher buckets
        const int p0 = cnt[b], p1 = cnt[b + 1];
        for (int p = p0; p < p1; ++p)        // exact in-bucket comparison (incl. self)
            risk += (sortedT[p] >= Ti) ? sortedE[p] : 0.f;
        local += (theta[i] - logf(risk)) * events[i];
    }

    // ---- P5: block reduce + write ----
    red[t] = local;
    __syncthreads();
    for (int s = NT / 2; s > 0; s >>= 1) {
        if (t < s) red[t] += red[t + s];
        __syncthreads();
    }
    if (t == 0) out[0] = -red[0] / (float)n;
}

// ---------- generic brute-force fallback (any n / tiny ws) ----------
#define BLOCK 256
__global__ void surv_partial_bf(const float* __restrict__ theta, const float* __restrict__ T,
                                const float* __restrict__ events, float* __restrict__ bsum, int n) {
    __shared__ float red[BLOCK];
    const int tid = threadIdx.x;
    const int i = blockIdx.x * BLOCK + tid;
    float term = 0.f;
    if (i < n) {
        const float Ti = T[i];
        float risk = 0.f;
        for (int j = 0; j < n; ++j)
            risk += (T[j] >= Ti) ? expf(theta[j]) : 0.f;
        term = (theta[i] - logf(risk)) * events[i];
    }
    red[tid] = term;
    __syncthreads();
    for (int s = BLOCK / 2; s > 0; s >>= 1) {
        if (tid < s) red[tid] += red[tid + s];
        __syncthreads();
    }
    if (tid == 0) bsum[blockIdx.x] = red[0];
}

__global__ void surv_final_bf(const float* __restrict__ bsum, float* __restrict__ out,
                              int nblocks, int n) {
    float v = 0.f;
    for (int b = threadIdx.x; b < nblocks; b += 64) v += bsum[b];
    for (int off = 32; off > 0; off >>= 1) v += __shfl_down(v, off, 64);
    if (threadIdx.x == 0) out[0] = -v / (float)n;
}

extern "C" void kernel_launch(void* const* d_in, const int* in_sizes, int n_in,
                              void* d_out, int out_size, void* d_ws, size_t ws_size,
                              hipStream_t stream) {
    const float* theta  = (const float*)d_in[0];
    const float* T      = (const float*)d_in[1];
    const float* events = (const float*)d_in[2];
    float* out = (float*)d_out;
    const int n = in_sizes[0];                      // 16384

    if (n == NT * EPT && ws_size >= (size_t)2 * n * sizeof(float)) {
        float* sortedT = (float*)d_ws;
        float* sortedE = sortedT + n;
        surv_one<<<1, NT, 0, stream>>>(theta, T, events, out, sortedT, sortedE, n);
    } else {
        const int nb = (n + BLOCK - 1) / BLOCK;
        float* bsum = (float*)d_ws;
        surv_partial_bf<<<nb, BLOCK, 0, stream>>>(theta, T, events, bsum, n);
        surv_final_bf<<<1, 64, 0, stream>>>(bsum, out, nb, n);
    }
}

// Round 6
// 107.360 us; speedup vs baseline: 2.4788x; 2.4788x over previous
//
#include <hip/hip_runtime.h>
#include <math.h>

#define BLOCK 256
#define NB 4096          // value buckets; monotone bucketing => exact algorithm
#define SCAN_T 1024
#define EPT (16384 / SCAN_T)   // 16 elements/thread in scatter phase

// K1: E=exp(theta), bucket id, rank via global atomic hist, bucket E-sums.
__global__ void surv_hist(const float* __restrict__ theta,
                          const float* __restrict__ T,
                          int* __restrict__ counts, float* __restrict__ bucketE,
                          float* __restrict__ Earr, int* __restrict__ elemB,
                          int* __restrict__ elemR, int n) {
    const int i = blockIdx.x * BLOCK + threadIdx.x;
    if (i >= n) return;
    const float Tg = T[i];
    const float E  = expf(theta[i]);
    int b = (int)((Tg + 6.0f) * ((float)NB / 12.0f));  // monotone in Tg -> order-exact
    b = min(max(b, 0), NB - 1);
    const int r = atomicAdd(&counts[b], 1);
    atomicAdd(&bucketE[b], E);
    Earr[i] = E; elemB[i] = b; elemR[i] = r;
}

// K2 (one block): scan hist in LDS (prefix counts -> offsets, suffix bucketE ->
// suffixE), write both, then counting-sort scatter all n elements.
__global__ void __launch_bounds__(SCAN_T)
surv_scan_scatter(const int* __restrict__ counts, const float* __restrict__ bucketE,
                  const float* __restrict__ T, const float* __restrict__ Earr,
                  const int* __restrict__ elemB, const int* __restrict__ elemR,
                  int* __restrict__ offsets, float* __restrict__ suffixE,
                  float* __restrict__ sortedT, float* __restrict__ sortedE, int n) {
    __shared__ int   cnt[NB + 1];
    __shared__ float be[NB + 1];
    __shared__ int   ci[SCAN_T];
    __shared__ float ce[SCAN_T];
    const int t = threadIdx.x;
    const int CH = NB / SCAN_T;                 // 4 buckets per thread
    const int base = t * CH;

    int cs = 0; float es = 0.f;
#pragma unroll
    for (int k = 0; k < CH; ++k) {
        cnt[base + k] = counts[base + k];
        be[base + k]  = bucketE[base + k];
        cs += cnt[base + k]; es += be[base + k];
    }
    ci[t] = cs; ce[t] = es;
    __syncthreads();
    for (int s = 1; s < SCAN_T; s <<= 1) {      // Hillis-Steele, 10 steps
        const int   a = (t >= s)          ? ci[t - s] : 0;
        const float f = (t + s < SCAN_T)  ? ce[t + s] : 0.f;
        __syncthreads();
        ci[t] += a; ce[t] += f;
        __syncthreads();
    }
    {
        int run = ci[t] - cs;                   // exclusive prefix of chunk sums
        float rs = ce[t] - es;                  // suffix strictly after this chunk
#pragma unroll
        for (int k = 0; k < CH; ++k) {
            const int c = cnt[base + k];
            cnt[base + k] = run; offsets[base + k] = run; run += c;
        }
#pragma unroll
        for (int k = CH - 1; k >= 0; --k) {
            rs += be[base + k];
            suffixE[base + k] = rs;
        }
    }
    if (t == 0) { offsets[NB] = n; suffixE[NB] = 0.f; }
    __syncthreads();

    // scatter: cnt[] in LDS now holds exclusive bucket offsets
#pragma unroll
    for (int k = 0; k < EPT; ++k) {
        const int i = k * SCAN_T + t;           // coalesced reads
        const int pos = cnt[elemB[i]] + elemR[i];
        sortedT[pos] = T[i];
        sortedE[pos] = Earr[i];
    }
}

// K3: risk + term + block reduce + fused grid-final via done-counter.
__global__ void surv_risk_final(const float* __restrict__ theta, const float* __restrict__ T,
                                const float* __restrict__ events,
                                const int* __restrict__ elemB, const int* __restrict__ offsets,
                                const float* __restrict__ suffixE,
                                const float* __restrict__ sortedT, const float* __restrict__ sortedE,
                                float* __restrict__ acc, int* __restrict__ done,
                                float* __restrict__ out, int n, int nblocks) {
    __shared__ float red[BLOCK];
    const int tid = threadIdx.x;
    const int i = blockIdx.x * BLOCK + tid;
    float term = 0.f;
    if (i < n) {
        const int b = elemB[i];
        const float Ti = T[i];
        float risk = suffixE[b + 1];            // all strictly-higher buckets
        const int p0 = offsets[b], p1 = offsets[b + 1];
        for (int p = p0; p < p1; ++p)           // exact in-bucket compare (incl. self)
            risk += (sortedT[p] >= Ti) ? sortedE[p] : 0.f;
        term = (theta[i] - logf(risk)) * events[i];
    }
    red[tid] = term;
    __syncthreads();
    for (int s = BLOCK / 2; s > 0; s >>= 1) {
        if (tid < s) red[tid] += red[tid + s];
        __syncthreads();
    }
    if (tid == 0) {
        atomicAdd(acc, red[0]);
        __threadfence();
        const int prev = atomicAdd(done, 1);
        if (prev == nblocks - 1) {
            const float total = atomicAdd(acc, 0.0f);  // coherent read
            out[0] = -total / (float)n;
        }
    }
}

// ---------- brute-force fallback (any n / tiny ws) ----------
__global__ void surv_partial_bf(const float* __restrict__ theta, const float* __restrict__ T,
                                const float* __restrict__ events, float* __restrict__ bsum, int n) {
    __shared__ float red[BLOCK];
    const int tid = threadIdx.x;
    const int i = blockIdx.x * BLOCK + tid;
    float term = 0.f;
    if (i < n) {
        const float Ti = T[i];
        float risk = 0.f;
        for (int j = 0; j < n; ++j)
            risk += (T[j] >= Ti) ? expf(theta[j]) : 0.f;
        term = (theta[i] - logf(risk)) * events[i];
    }
    red[tid] = term;
    __syncthreads();
    for (int s = BLOCK / 2; s > 0; s >>= 1) {
        if (tid < s) red[tid] += red[tid + s];
        __syncthreads();
    }
    if (tid == 0) bsum[blockIdx.x] = red[0];
}

__global__ void surv_final_bf(const float* __restrict__ bsum, float* __restrict__ out,
                              int nblocks, int n) {
    float v = 0.f;
    for (int b = threadIdx.x; b < nblocks; b += 64) v += bsum[b];
    for (int off = 32; off > 0; off >>= 1) v += __shfl_down(v, off, 64);
    if (threadIdx.x == 0) out[0] = -v / (float)n;
}

extern "C" void kernel_launch(void* const* d_in, const int* in_sizes, int n_in,
                              void* d_out, int out_size, void* d_ws, size_t ws_size,
                              hipStream_t stream) {
    const float* theta  = (const float*)d_in[0];
    const float* T      = (const float*)d_in[1];
    const float* events = (const float*)d_in[2];
    float* out = (float*)d_out;
    const int n = in_sizes[0];                  // 16384
    const int nbi = (n + BLOCK - 1) / BLOCK;    // 64

    // ws layout (4B units), zero region first (one memset):
    //  [counts NB][bucketE NB][acc][done] | offsets[NB+1] suffixE[NB+1]
    //  Earr[n] elemB[n] elemR[n] sortedT[n] sortedE[n]
    const size_t zero_words = (size_t)2 * NB + 2;
    const size_t need = (zero_words + 2 * (NB + 1) + 5 * (size_t)n) * 4;

    if (n != SCAN_T * EPT || ws_size < need) {
        float* bsum = (float*)d_ws;
        surv_partial_bf<<<nbi, BLOCK, 0, stream>>>(theta, T, events, bsum, n);
        surv_final_bf<<<1, 64, 0, stream>>>(bsum, out, nbi, n);
        return;
    }

    int*   counts  = (int*)d_ws;
    float* bucketE = (float*)(counts + NB);
    float* acc     = bucketE + NB;
    int*   done    = (int*)(acc + 1);
    int*   offsets = done + 1;
    float* suffixE = (float*)(offsets + NB + 1);
    float* Earr    = suffixE + NB + 1;
    int*   elemB   = (int*)(Earr + n);
    int*   elemR   = elemB + n;
    float* sortedT = (float*)(elemR + n);
    float* sortedE = sortedT + n;

    hipMemsetAsync(d_ws, 0, zero_words * 4, stream);   // counts+bucketE+acc+done
    surv_hist<<<nbi, BLOCK, 0, stream>>>(theta, T, counts, bucketE, Earr, elemB, elemR, n);
    surv_scan_scatter<<<1, SCAN_T, 0, stream>>>(counts, bucketE, T, Earr, elemB, elemR,
                                                offsets, suffixE, sortedT, sortedE, n);
    surv_risk_final<<<nbi, BLOCK, 0, stream>>>(theta, T, events, elemB, offsets, suffixE,
                                               sortedT, sortedE, acc, done, out, n, nbi);
}

// Round 7
// 82.230 us; speedup vs baseline: 3.2363x; 1.3056x over previous
//
#include <hip/hip_runtime.h>
#include <math.h>

#define BLOCK 256
#define NB 4096          // value buckets; monotone bucketing => exact algorithm
#define SCAN_T 1024

// K1: E=exp(theta), bucket id, rank via global atomic hist, bucket E-sums.
// elemBR packs (bucket<<16 | rank): both < 2^16.
__global__ void surv_hist(const float* __restrict__ theta,
                          const float* __restrict__ T,
                          int* __restrict__ counts, float* __restrict__ bucketE,
                          float* __restrict__ Earr, int* __restrict__ elemBR, int n) {
    const int i = blockIdx.x * BLOCK + threadIdx.x;
    if (i >= n) return;
    const float Tg = T[i];
    const float E  = expf(theta[i]);
    int b = (int)((Tg + 6.0f) * ((float)NB / 12.0f));  // monotone in Tg -> order-exact
    b = min(max(b, 0), NB - 1);
    const int r = atomicAdd(&counts[b], 1);
    atomicAdd(&bucketE[b], E);
    Earr[i] = E;
    elemBR[i] = (b << 16) | r;
}

// K2 (one block, 32KB in / 32KB out only): exclusive-prefix counts -> offsets,
// inclusive-suffix bucketE -> suffixE.
__global__ void __launch_bounds__(SCAN_T)
surv_scan(const int* __restrict__ counts, const float* __restrict__ bucketE,
          int* __restrict__ offsets, float* __restrict__ suffixE, int n) {
    __shared__ int   ci[SCAN_T];
    __shared__ float ce[SCAN_T];
    const int t = threadIdx.x;
    const int CH = NB / SCAN_T;                 // 4 buckets per thread
    const int base = t * CH;
    int cl[CH]; float el[CH];
    int cs = 0; float es = 0.f;
#pragma unroll
    for (int k = 0; k < CH; ++k) {
        cl[k] = counts[base + k]; el[k] = bucketE[base + k];
        cs += cl[k]; es += el[k];
    }
    ci[t] = cs; ce[t] = es;
    __syncthreads();
    for (int s = 1; s < SCAN_T; s <<= 1) {      // Hillis-Steele, 10 steps
        const int   a = (t >= s)          ? ci[t - s] : 0;
        const float f = (t + s < SCAN_T)  ? ce[t + s] : 0.f;
        __syncthreads();
        ci[t] += a; ce[t] += f;
        __syncthreads();
    }
    int run = ci[t] - cs;                       // exclusive prefix of chunk sums
    float rs = ce[t] - es;                      // suffix strictly after this chunk
#pragma unroll
    for (int k = 0; k < CH; ++k) { offsets[base + k] = run; run += cl[k]; }
#pragma unroll
    for (int k = CH - 1; k >= 0; --k) { rs += el[k]; suffixE[base + k] = rs; }
    if (t == 0) { offsets[NB] = n; suffixE[NB] = 0.f; }
}

// K3: counting-sort scatter (multi-CU).
__global__ void surv_scatter(const float* __restrict__ T, const float* __restrict__ Earr,
                             const int* __restrict__ elemBR, const int* __restrict__ offsets,
                             float* __restrict__ sortedT, float* __restrict__ sortedE, int n) {
    const int i = blockIdx.x * BLOCK + threadIdx.x;
    if (i >= n) return;
    const int br = elemBR[i];
    const int pos = offsets[br >> 16] + (br & 0xFFFF);
    sortedT[pos] = T[i];
    sortedE[pos] = Earr[i];
}

// K4: risk + term + block reduce + fused grid-final via done-counter.
__global__ void surv_risk_final(const float* __restrict__ theta, const float* __restrict__ T,
                                const float* __restrict__ events,
                                const int* __restrict__ offsets,
                                const float* __restrict__ suffixE,
                                const float* __restrict__ sortedT, const float* __restrict__ sortedE,
                                float* __restrict__ acc, int* __restrict__ done,
                                float* __restrict__ out, int n, int nblocks) {
    __shared__ float red[BLOCK];
    const int tid = threadIdx.x;
    const int i = blockIdx.x * BLOCK + tid;
    float term = 0.f;
    if (i < n) {
        const float Ti = T[i];
        int b = (int)((Ti + 6.0f) * ((float)NB / 12.0f));   // recompute (cheaper than load)
        b = min(max(b, 0), NB - 1);
        float risk = suffixE[b + 1];            // all strictly-higher buckets
        const int p0 = offsets[b], p1 = offsets[b + 1];
        for (int p = p0; p < p1; ++p)           // exact in-bucket compare (incl. self)
            risk += (sortedT[p] >= Ti) ? sortedE[p] : 0.f;
        term = (theta[i] - logf(risk)) * events[i];
    }
    red[tid] = term;
    __syncthreads();
    for (int s = BLOCK / 2; s > 0; s >>= 1) {
        if (tid < s) red[tid] += red[tid + s];
        __syncthreads();
    }
    if (tid == 0) {
        atomicAdd(acc, red[0]);
        __threadfence();
        const int prev = atomicAdd(done, 1);
        if (prev == nblocks - 1) {
            const float total = atomicAdd(acc, 0.0f);  // coherent read-back
            out[0] = -total / (float)n;
        }
    }
}

// ---------- brute-force fallback (any n / tiny ws) ----------
__global__ void surv_partial_bf(const float* __restrict__ theta, const float* __restrict__ T,
                                const float* __restrict__ events, float* __restrict__ bsum, int n) {
    __shared__ float red[BLOCK];
    const int tid = threadIdx.x;
    const int i = blockIdx.x * BLOCK + tid;
    float term = 0.f;
    if (i < n) {
        const float Ti = T[i];
        float risk = 0.f;
        for (int j = 0; j < n; ++j)
            risk += (T[j] >= Ti) ? expf(theta[j]) : 0.f;
        term = (theta[i] - logf(risk)) * events[i];
    }
    red[tid] = term;
    __syncthreads();
    for (int s = BLOCK / 2; s > 0; s >>= 1) {
        if (tid < s) red[tid] += red[tid + s];
        __syncthreads();
    }
    if (tid == 0) bsum[blockIdx.x] = red[0];
}

__global__ void surv_final_bf(const float* __restrict__ bsum, float* __restrict__ out,
                              int nblocks, int n) {
    float v = 0.f;
    for (int b = threadIdx.x; b < nblocks; b += 64) v += bsum[b];
    for (int off = 32; off > 0; off >>= 1) v += __shfl_down(v, off, 64);
    if (threadIdx.x == 0) out[0] = -v / (float)n;
}

extern "C" void kernel_launch(void* const* d_in, const int* in_sizes, int n_in,
                              void* d_out, int out_size, void* d_ws, size_t ws_size,
                              hipStream_t stream) {
    const float* theta  = (const float*)d_in[0];
    const float* T      = (const float*)d_in[1];
    const float* events = (const float*)d_in[2];
    float* out = (float*)d_out;
    const int n = in_sizes[0];                  // 16384
    const int nbi = (n + BLOCK - 1) / BLOCK;    // 64

    // ws layout (4B words), zero region first (one memset):
    //  [counts NB][bucketE NB][acc][done] | offsets[NB+1] suffixE[NB+1]
    //  Earr[n] elemBR[n] sortedT[n] sortedE[n]
    const size_t zero_words = (size_t)2 * NB + 2;
    const size_t need = (zero_words + 2 * (NB + 1) + 4 * (size_t)n) * 4;

    // n must fit the 16-bit rank pack and the bucket count assumptions
    if (n >= (1 << 16) || ws_size < need) {
        float* bsum = (float*)d_ws;
        surv_partial_bf<<<nbi, BLOCK, 0, stream>>>(theta, T, events, bsum, n);
        surv_final_bf<<<1, 64, 0, stream>>>(bsum, out, nbi, n);
        return;
    }

    int*   counts  = (int*)d_ws;
    float* bucketE = (float*)(counts + NB);
    float* acc     = bucketE + NB;
    int*   done    = (int*)(acc + 1);
    int*   offsets = done + 1;
    float* suffixE = (float*)(offsets + NB + 1);
    float* Earr    = suffixE + NB + 1;
    int*   elemBR  = (int*)(Earr + n);
    float* sortedT = (float*)(elemBR + n);
    float* sortedE = sortedT + n;

    hipMemsetAsync(d_ws, 0, zero_words * 4, stream);   // counts+bucketE+acc+done
    surv_hist<<<nbi, BLOCK, 0, stream>>>(theta, T, counts, bucketE, Earr, elemBR, n);
    surv_scan<<<1, SCAN_T, 0, stream>>>(counts, bucketE, offsets, suffixE, n);
    surv_scatter<<<nbi, BLOCK, 0, stream>>>(T, Earr, elemBR, offsets, sortedT, sortedE, n);
    surv_risk_final<<<nbi, BLOCK, 0, stream>>>(theta, T, events, offsets, suffixE,
                                               sortedT, sortedE, acc, done, out, n, nbi);
}